// Round 2
// baseline (269.989 us; speedup 1.0000x reference)
//
#include <hip/hip_runtime.h>

#define NBINS 256
#define NCH 3
#define HSIZE (NBINS * NCH)   // 768
#define NWAVE 4               // private histogram copies per block (one per wave)
#define SLOTS 8               // global partial-histogram copies
#define TPB 256
#define BLOCKS 2048

typedef float f4 __attribute__((ext_vector_type(4)));

__global__ __launch_bounds__(TPB) void hist_kernel(const float* __restrict__ in,
                                                   unsigned int* __restrict__ ws,
                                                   int n) {
    __shared__ unsigned int lds[NWAVE][HSIZE];

    const int tid = threadIdx.x;

    // zero LDS (3072 words / 256 threads = 12 each)
    unsigned int* flat = &lds[0][0];
    #pragma unroll
    for (int i = 0; i < NWAVE * HSIZE / TPB; ++i)
        flat[tid + i * TPB] = 0u;
    __syncthreads();

    unsigned int* h = lds[tid >> 6];

    // Each thread owns groups of 12 consecutive floats (= 4 RGB pixels = 3 float4).
    // Group base element 12*g is always channel 0 -> channel pattern is STATIC:
    //   f4 a (elems 0..3):  ch 0,1,2,0
    //   f4 b (elems 4..7):  ch 1,2,0,1
    //   f4 c (elems 8..11): ch 2,0,1,2
    const long long ngrp   = n / 12;
    const long long stride = (long long)gridDim.x * TPB;
    const f4* __restrict__ in4 = (const f4*)in;

    #pragma unroll 2
    for (long long g = (long long)blockIdx.x * TPB + tid; g < ngrp; g += stride) {
        const f4* p = in4 + 3 * g;
        f4 a = __builtin_nontemporal_load(p + 0);
        f4 b = __builtin_nontemporal_load(p + 1);
        f4 c = __builtin_nontemporal_load(p + 2);

        int a0 = min(max((int)(a.x * 256.0f), 0), 255);
        int a1 = min(max((int)(a.y * 256.0f), 0), 255);
        int a2 = min(max((int)(a.z * 256.0f), 0), 255);
        int a3 = min(max((int)(a.w * 256.0f), 0), 255);
        int b0 = min(max((int)(b.x * 256.0f), 0), 255);
        int b1 = min(max((int)(b.y * 256.0f), 0), 255);
        int b2 = min(max((int)(b.z * 256.0f), 0), 255);
        int b3 = min(max((int)(b.w * 256.0f), 0), 255);
        int c0 = min(max((int)(c.x * 256.0f), 0), 255);
        int c1 = min(max((int)(c.y * 256.0f), 0), 255);
        int c2 = min(max((int)(c.z * 256.0f), 0), 255);
        int c3 = min(max((int)(c.w * 256.0f), 0), 255);

        atomicAdd(&h[0 * NBINS + a0], 1u);
        atomicAdd(&h[1 * NBINS + a1], 1u);
        atomicAdd(&h[2 * NBINS + a2], 1u);
        atomicAdd(&h[0 * NBINS + a3], 1u);
        atomicAdd(&h[1 * NBINS + b0], 1u);
        atomicAdd(&h[2 * NBINS + b1], 1u);
        atomicAdd(&h[0 * NBINS + b2], 1u);
        atomicAdd(&h[1 * NBINS + b3], 1u);
        atomicAdd(&h[2 * NBINS + c0], 1u);
        atomicAdd(&h[0 * NBINS + c1], 1u);
        atomicAdd(&h[1 * NBINS + c2], 1u);
        atomicAdd(&h[2 * NBINS + c3], 1u);
    }

    // scalar tail (n not divisible by 12) — only block 0
    if (blockIdx.x == 0) {
        for (long long e = ngrp * 12 + tid; e < n; e += TPB) {
            float x = in[e];
            int bin = min(max((int)(x * 256.0f), 0), 255);
            int ch = (int)(e % 3);
            atomicAdd(&h[ch * NBINS + bin], 1u);
        }
    }

    __syncthreads();

    // flush: sum the 4 wave copies, one global atomic per bin per block
    unsigned int* dst = ws + (blockIdx.x & (SLOTS - 1)) * HSIZE;
    #pragma unroll
    for (int i = 0; i < HSIZE / TPB; ++i) {
        int idx = tid + i * TPB;
        unsigned int s = lds[0][idx] + lds[1][idx] + lds[2][idx] + lds[3][idx];
        if (s) atomicAdd(&dst[idx], s);
    }
}

__global__ void finalize_kernel(const unsigned int* __restrict__ ws,
                                float* __restrict__ out,
                                float total) {
    int t = threadIdx.x;          // 0..767
    int bin = t / 3;
    int c = t - 3 * bin;
    unsigned int s = 0;
    #pragma unroll
    for (int k = 0; k < SLOTS; ++k)
        s += ws[k * HSIZE + c * NBINS + bin];
    out[t] = (float)s / total;    // out layout: [bin, channel]
}

extern "C" void kernel_launch(void* const* d_in, const int* in_sizes, int n_in,
                              void* d_out, int out_size, void* d_ws, size_t ws_size,
                              hipStream_t stream) {
    const float* in = (const float*)d_in[0];
    const int n = in_sizes[0];
    unsigned int* ws = (unsigned int*)d_ws;

    hipMemsetAsync(ws, 0, SLOTS * HSIZE * sizeof(unsigned int), stream);
    hist_kernel<<<BLOCKS, TPB, 0, stream>>>(in, ws, n);
    finalize_kernel<<<1, HSIZE, 0, stream>>>(ws, (float*)d_out, (float)(n / NCH));
}